// Round 7
// baseline (304.883 us; speedup 1.0000x reference)
//
#include <hip/hip_runtime.h>
#include <stdint.h>

#define B_ 8
#define K_ 8
#define N_ 128
#define D_ 256
#define H_ 128
#define NNEG_ 64

typedef unsigned long long u64;
typedef float f4 __attribute__((ext_vector_type(4)));

// ---------------------------------------------------------------------------
// u64 wave shuffles + bitonic helpers
// ---------------------------------------------------------------------------
__device__ __forceinline__ u64 shfl_xor_u64(u64 v, int m) {
    int lo = __shfl_xor((int)(unsigned)v, m, 64);
    int hi = __shfl_xor((int)(unsigned)(v >> 32), m, 64);
    return ((u64)(unsigned)hi << 32) | (unsigned)lo;
}
// cleanup merge of a bitonic 64-seq -> ascending across lanes
__device__ __forceinline__ u64 bitonic_merge64(u64 m, int lane) {
#pragma unroll
    for (int j = 32; j > 0; j >>= 1) {
        u64 o = shfl_xor_u64(m, j);
        bool keepMin = ((lane & j) == 0);
        bool lt = m < o;
        m = (keepMin == lt) ? m : o;
    }
    return m;
}
// top-64 of union of two ascending sorted 64-lists (one elem/lane), ascending
__device__ __forceinline__ u64 merge2(u64 a, u64 b, int lane) {
    u64 br = shfl_xor_u64(b, 63);   // b[63-lane]
    u64 m = a < br ? a : br;
    return bitonic_merge64(m, lane);
}
__device__ __forceinline__ unsigned sortable(float f) {
    unsigned u = __float_as_uint(f);
    return (u & 0x80000000u) ? ~u : (u | 0x80000000u);
}
__device__ __forceinline__ float unsortable(unsigned u) {
    return __uint_as_float((u & 0x80000000u) ? (u & 0x7FFFFFFFu) : ~u);
}
// full ascending sort of 128 elems held 2/lane in registers (wave-local)
__device__ __forceinline__ void sort128_reg(u64& v0, u64& v1, int lane) {
#pragma unroll
    for (int k = 2; k <= 64; k <<= 1) {
        bool d0 = ((lane & k) == 0);
        bool d1 = (k == 64) ? false : d0;
#pragma unroll
        for (int j = k >> 1; j > 0; j >>= 1) {
            u64 o0 = shfl_xor_u64(v0, j);
            bool km0 = (((lane & j) == 0) == d0);
            v0 = (km0 == (v0 < o0)) ? v0 : o0;
            u64 o1 = shfl_xor_u64(v1, j);
            bool km1 = (((lane & j) == 0) == d1);
            v1 = (km1 == (v1 < o1)) ? v1 : o1;
        }
    }
    if (v0 > v1) { u64 tmp = v0; v0 = v1; v1 = tmp; }
#pragma unroll
    for (int j = 32; j > 0; j >>= 1) {
        bool km = ((lane & j) == 0);
        u64 o0 = shfl_xor_u64(v0, j);
        v0 = (km == (v0 < o0)) ? v0 : o0;
        u64 o1 = shfl_xor_u64(v1, j);
        v1 = (km == (v1 < o1)) ? v1 : o1;
    }
}

// ---------------------------------------------------------------------------
// g1: 4 GEMMs + is_target.  64x64 tiles, 64 threads (ONE wave), 8x8/thread.
// Ratio 16 FMA per ds_read_b128 (8 A + 8 B reads per 256 FMAs per 4-k group)
// -> LDS-pipe floor ~18us.  LDS double-buffered, one (1-wave, cheap) barrier
// per 32-k chunk.  K ascending per output -> bit-exact vs all prior rounds.
// Blocks: [0,256) HU0, [256,384) HU1n, [384,640) HP0, [640,896) HP1,
// [896,900) is_target.  bid2 = 2*rowtile + colhalf.
// ---------------------------------------------------------------------------
__global__ __launch_bounds__(64) void g1_gemm(
    const float* __restrict__ pos, const float* __restrict__ neg,
    const float* __restrict__ Wu1, const float* __restrict__ Wp1,
    const int* __restrict__ pos_classes, const int* __restrict__ target_class,
    float* __restrict__ HU0, float* __restrict__ HU1n,
    float* __restrict__ HP0, float* __restrict__ HP1,
    float* __restrict__ outp) {
    int bid = blockIdx.x;
    int t = threadIdx.x;
    if (bid >= 896) {
        int base = (bid - 896) * 2048 + t * 32;
#pragma unroll
        for (int q = 0; q < 32; ++q) {
            int idx = base + q;
            outp[64 + idx] = (pos_classes[idx] == target_class[idx >> 10]) ? 1.0f : 0.0f;
        }
        return;
    }
    const float* A; const float* W; float* OUT; int bid2;
    if (bid < 256)      { A = pos; W = Wu1;           OUT = HU0;  bid2 = bid; }
    else if (bid < 384) { A = neg; W = Wu1 + D_ * H_; OUT = HU1n; bid2 = bid - 256; }
    else if (bid < 640) { A = pos; W = Wp1;           OUT = HP0;  bid2 = bid - 384; }
    else                { A = pos; W = Wp1 + D_ * H_; OUT = HP1;  bid2 = bid - 640; }
    int rb = (bid2 >> 1) * 64;      // row base
    int cb64 = (bid2 & 1) * 64;     // col base (0 or 64)

    __shared__ float As[2][64][36];    // [buf][row][k], row-major, pad->36
    __shared__ float Bs[2][32][64];    // [buf][kk][col_local]
    int tx = t & 7, ty = t >> 3;       // tx: col oct (8 cols); ty: row oct (8 rows)
    f4 acc[8][2];
#pragma unroll
    for (int i = 0; i < 8; ++i) { acc[i][0] = (f4)0.f; acc[i][1] = (f4)0.f; }

    // stage chunk 0 into buffer 0
#pragma unroll
    for (int rep = 0; rep < 8; ++rep) {
        int flat = t + rep * 64;           // 0..511
        int row = flat >> 3, kq = flat & 7;
        *(f4*)&As[0][row][kq * 4] = *(const f4*)&A[(size_t)(rb + row) * D_ + kq * 4];
    }
#pragma unroll
    for (int rep = 0; rep < 8; ++rep) {
        int flat = t + rep * 64;           // 0..511
        int kr = flat >> 4, cq = flat & 15;
        *(f4*)&Bs[0][kr][cq * 4] = *(const f4*)&W[(size_t)kr * H_ + cb64 + cq * 4];
    }
    __syncthreads();

    for (int chunk = 0; chunk < 8; ++chunk) {
        int cur = chunk & 1, nxt = cur ^ 1;
        bool pre = (chunk < 7);
        f4 pa[8], pb[8];
        if (pre) {
            int k0n = (chunk + 1) * 32;
#pragma unroll
            for (int rep = 0; rep < 8; ++rep) {
                int flat = t + rep * 64;
                int row = flat >> 3, kq = flat & 7;
                pa[rep] = *(const f4*)&A[(size_t)(rb + row) * D_ + k0n + kq * 4];
            }
#pragma unroll
            for (int rep = 0; rep < 8; ++rep) {
                int flat = t + rep * 64;
                int kr = flat >> 4, cq = flat & 15;
                pb[rep] = *(const f4*)&W[(size_t)(k0n + kr) * H_ + cb64 + cq * 4];
            }
        }
#pragma unroll
        for (int g = 0; g < 8; ++g) {
            // A: 8 rows x 4 k-values each (1 b128 per row)
            f4 av[8];
#pragma unroll
            for (int i = 0; i < 8; ++i)
                av[i] = *(const f4*)&As[cur][ty * 8 + i][g * 4];
            // per k within group: 2 b128 B reads, 64 FMAs
#pragma unroll
            for (int q = 0; q < 4; ++q) {
                f4 b0 = *(const f4*)&Bs[cur][g * 4 + q][tx * 8];
                f4 b1 = *(const f4*)&Bs[cur][g * 4 + q][tx * 8 + 4];
#pragma unroll
                for (int i = 0; i < 8; ++i) {
                    float a = av[i][q];
                    acc[i][0][0] += a * b0[0]; acc[i][0][1] += a * b0[1];
                    acc[i][0][2] += a * b0[2]; acc[i][0][3] += a * b0[3];
                    acc[i][1][0] += a * b1[0]; acc[i][1][1] += a * b1[1];
                    acc[i][1][2] += a * b1[2]; acc[i][1][3] += a * b1[3];
                }
            }
        }
        if (pre) {
#pragma unroll
            for (int rep = 0; rep < 8; ++rep) {
                int flat = t + rep * 64;
                int row = flat >> 3, kq = flat & 7;
                *(f4*)&As[nxt][row][kq * 4] = pa[rep];
            }
#pragma unroll
            for (int rep = 0; rep < 8; ++rep) {
                int flat = t + rep * 64;
                int kr = flat >> 4, cq = flat & 15;
                *(f4*)&Bs[nxt][kr][cq * 4] = pb[rep];
            }
        }
        __syncthreads();
    }
#pragma unroll
    for (int i = 0; i < 8; ++i) {
        *(f4*)&OUT[(size_t)(rb + ty * 8 + i) * H_ + cb64 + tx * 8] = acc[i][0];
        *(f4*)&OUT[(size_t)(rb + ty * 8 + i) * H_ + cb64 + tx * 8 + 4] = acc[i][1];
    }
}

// ---------------------------------------------------------------------------
// g2: blocks 0..255 = ue (t0), blocks 256..511 = score0 (sc0 = dot + bp2).
// 128 threads, 4m x 4n per thread.  ue reduction tree identical to prior
// rounds -> bit-exact.  sc0: h ascending -> bit-exact.
// ---------------------------------------------------------------------------
__global__ __launch_bounds__(128) void g2_ue_sc0(
    const float* __restrict__ HU0, const float* __restrict__ HU1n,
    const float* __restrict__ bu1, const float* __restrict__ Wu2,
    const float* __restrict__ bu2v,
    const float* __restrict__ HP0, const float* __restrict__ HP1,
    const float* __restrict__ bp1, const float* __restrict__ Wp2,
    const float* __restrict__ bp2,
    float* __restrict__ t0, float* __restrict__ sc0) {
    __shared__ float LsT[128][36];   // [h][m], m<32
    __shared__ float RsT[128][68];   // [h][n], n<64
    __shared__ float wsv[128];
    __shared__ float red[32][33];

    int bid = blockIdx.x;
    int t = threadIdx.x;
    bool is_ue = bid < 256;

    const float* Lsrc; const float* Rsrc; const float* b1v; const float* W2;
    if (is_ue) {
        int bk = bid >> 2, mt = bid & 3;
        Lsrc = HU0 + (size_t)(bk * N_ + mt * 32) * H_;
        Rsrc = HU1n + (size_t)bk * NNEG_ * H_;
        b1v = bu1; W2 = Wu2;
    } else {
        int bid2 = bid - 256;
        int b = bid2 >> 3, m0t = (bid2 >> 1) & 3, m1t = bid2 & 1;
        Lsrc = HP0 + (size_t)b * 2 * N_ * H_ + m0t * 32 * H_;
        Rsrc = HP1 + (size_t)b * 2 * N_ * H_ + N_ * H_ + m1t * 64 * H_;
        b1v = bp1; W2 = Wp2;
    }
    // stage L transposed (+b1): 32 m x 32 h-quads; m-fastest (conflict-free)
    for (int i = t; i < 32 * 32; i += 128) {
        int m = i & 31, hq = i >> 5;
        const f4 a = *(const f4*)&Lsrc[(size_t)m * H_ + hq * 4];
        const f4 b = *(const f4*)&b1v[hq * 4];
        LsT[hq * 4 + 0][m] = a[0] + b[0];
        LsT[hq * 4 + 1][m] = a[1] + b[1];
        LsT[hq * 4 + 2][m] = a[2] + b[2];
        LsT[hq * 4 + 3][m] = a[3] + b[3];
    }
    // stage R transposed: 64 n x 32 h-quads; n-fastest (2-way = free)
    for (int i = t; i < 64 * 32; i += 128) {
        int n = i & 63, hq = i >> 6;
        const f4 a = *(const f4*)&Rsrc[(size_t)n * H_ + hq * 4];
        RsT[hq * 4 + 0][n] = a[0];
        RsT[hq * 4 + 1][n] = a[1];
        RsT[hq * 4 + 2][n] = a[2];
        RsT[hq * 4 + 3][n] = a[3];
    }
    wsv[t] = W2[t];
    __syncthreads();

    int tm = t & 7, tn = t >> 3;    // m = tm*4+i (32), n = tn*4+j (64)
    f4 acc[4];
#pragma unroll
    for (int i = 0; i < 4; ++i) acc[i] = (f4)0.f;
#pragma unroll 2
    for (int hg = 0; hg < 32; ++hg) {
        f4 wv = *(const f4*)&wsv[hg * 4];
        f4 lv[4], rv[4];
#pragma unroll
        for (int s = 0; s < 4; ++s) {
            lv[s] = *(const f4*)&LsT[hg * 4 + s][tm * 4];
            rv[s] = *(const f4*)&RsT[hg * 4 + s][tn * 4];
        }
#pragma unroll
        for (int s = 0; s < 4; ++s) {
            float w = wv[s];
#pragma unroll
            for (int i = 0; i < 4; ++i) {
                float l = lv[s][i];
                float v;
                v = l + rv[s][0]; v = v > 0.f ? v : 0.f; acc[i][0] += v * w;
                v = l + rv[s][1]; v = v > 0.f ? v : 0.f; acc[i][1] += v * w;
                v = l + rv[s][2]; v = v > 0.f ? v : 0.f; acc[i][2] += v * w;
                v = l + rv[s][3]; v = v > 0.f ? v : 0.f; acc[i][3] += v * w;
            }
        }
    }

    if (is_ue) {
        int bk = bid >> 2, mt = bid & 3;
#pragma unroll
        for (int i = 0; i < 4; ++i) {
            red[tm * 4 + i][tn * 2 + 0] = acc[i][0] + acc[i][1];
            red[tm * 4 + i][tn * 2 + 1] = acc[i][2] + acc[i][3];
        }
        __syncthreads();
        if (t < 32) {
            float s = 0.f;
            for (int q = 0; q < 32; ++q) s += red[t][q];
            t0[bk * N_ + mt * 32 + t] = s * (1.0f / NNEG_) + bu2v[0];
        }
    } else {
        int bid2 = bid - 256;
        int b = bid2 >> 3, m0t = (bid2 >> 1) & 3, m1t = bid2 & 1;
        float bp2v = bp2[0];
        float* orow = sc0 + (size_t)b * 16384;
#pragma unroll
        for (int i = 0; i < 4; ++i) {
            int m0 = m0t * 32 + tm * 4 + i;
            int m1 = m1t * 64 + tn * 4;
            f4 o = {acc[i][0] + bp2v, acc[i][1] + bp2v,
                    acc[i][2] + bp2v, acc[i][3] + bp2v};
            *(f4*)&orow[m0 * 128 + m1] = o;
        }
    }
}

// ---------------------------------------------------------------------------
// g3a: level-0 chunk top-64.  256 blocks (row r, chunk c of 8) x 256.
// Per-wave ballot radix-descent -> compact -> register sort-128 -> merge 4.
// ---------------------------------------------------------------------------
__global__ __launch_bounds__(256) void g3a_top0(const float* __restrict__ sc0,
                                                const float* __restrict__ t0,
                                                u64* __restrict__ g3c) {
    int bid = blockIdx.x;
    int r = bid >> 3, c = bid & 7;
    int t = threadIdx.x, lane = t & 63, w = t >> 6;
    __shared__ float tt[256];
    __shared__ u64 cand[4][128];
    if (t < 256) tt[t] = t0[r * 256 + t];
    __syncthreads();
    const float* row = sc0 + (size_t)r * 16384 + c * 2048 + w * 512;
    unsigned sv[8];
#pragma unroll
    for (int j = 0; j < 8; ++j) {
        int li = j * 64 + lane;
        int idx = c * 2048 + w * 512 + li;
        float v = (tt[idx >> 7] + tt[128 + (idx & 127)]) - row[li];
        sv[j] = sortable(v);
    }
    // per-wave exact rank-63 threshold over this wave's 512 values
    unsigned T = 0u;
#pragma unroll
    for (int it = 0; it < 16; ++it) {
        int p = 30 - 2 * it;
        unsigned C1 = T | (1u << p), C2 = T | (2u << p), C3 = T | (3u << p);
        unsigned c1 = 0u, c2 = 0u, c3 = 0u;
#pragma unroll
        for (int j = 0; j < 8; ++j) {
            c1 += (unsigned)__popcll(__ballot(sv[j] < C1));
            c2 += (unsigned)__popcll(__ballot(sv[j] < C2));
            c3 += (unsigned)__popcll(__ballot(sv[j] < C3));
        }
        unsigned k = (c3 < 64u) ? 3u : (c2 < 64u) ? 2u : (c1 < 64u) ? 1u : 0u;
        T |= (k << p);
    }
    // compact candidates (sv <= T), deterministic ballot-prefix, cap 128
    u64* my = cand[w];
    int base = 0;
#pragma unroll
    for (int j = 0; j < 8; ++j) {
        u64 mask = __ballot(sv[j] <= T);
        if (sv[j] <= T) {
            int pos = base + (int)__popcll(mask & ((1ull << lane) - 1ull));
            if (pos < 128) {
                int idx = c * 2048 + w * 512 + j * 64 + lane;
                my[pos] = ((u64)sv[j] << 32) | (unsigned)idx;
            }
        }
        base += (int)__popcll(mask);
    }
    int cc = base < 128 ? base : 128;
    u64 v0 = (lane < cc) ? my[lane] : ~0ull;
    u64 v1 = (64 + lane < cc) ? my[64 + lane] : ~0ull;
    sort128_reg(v0, v1, lane);
    my[lane] = v0;   // wave's sorted top-64
    __syncthreads();
    if (w == 0) {
        u64 x0 = cand[0][lane], x1 = cand[1][lane];
        u64 x2 = cand[2][lane], x3 = cand[3][lane];
        u64 y0 = merge2(x0, x1, lane), y1 = merge2(x2, x3, lane);
        g3c[(size_t)bid * 64 + lane] = merge2(y0, y1, lane);
    }
}

// ---------------------------------------------------------------------------
// g4a: (fused g3b) row-merge + level-1 scoring + chunk top-64.
// 128 blocks (unit u, m-quarter mq, n-half nh) x 256.
// ---------------------------------------------------------------------------
__global__ __launch_bounds__(256) void g4a_s1(
    const float* __restrict__ HP0, const float* __restrict__ HP1,
    const u64* __restrict__ g3c, int* __restrict__ pA,
    const float* __restrict__ bp1, const float* __restrict__ Wp2,
    const float* __restrict__ bp2, u64* __restrict__ g4top) {
    int bid = blockIdx.x;
    int u = bid >> 3, mq = (bid >> 1) & 3, nh = bid & 1;
    int t = threadIdx.x, lane = t & 63, w = t >> 6;
    __shared__ float LsT[128][17];   // [h][m_local], 16 m rows
    __shared__ float RsT[128][34];   // [h][n_local], 32 n cols
    __shared__ float taL[64], taR[64];
    __shared__ int paL[64], paR[64];
    __shared__ float wsv[128];
    __shared__ u64 cand[4][64];
    // fused g3b: waves 0/1 merge rows 2u / 2u+1 (8 sorted 64-lists each)
    if (w < 2) {
        const u64* Lp = g3c + (size_t)(2 * u + w) * 512;
        u64 x0 = Lp[lane], x1 = Lp[64 + lane], x2 = Lp[128 + lane], x3 = Lp[192 + lane];
        u64 x4 = Lp[256 + lane], x5 = Lp[320 + lane], x6 = Lp[384 + lane], x7 = Lp[448 + lane];
        u64 y0 = merge2(x0, x1, lane), y1 = merge2(x2, x3, lane);
        u64 y2 = merge2(x4, x5, lane), y3 = merge2(x6, x7, lane);
        u64 z0 = merge2(y0, y1, lane), z1 = merge2(y2, y3, lane);
        u64 f = merge2(z0, z1, lane);
        int idx = (int)(f & 0xFFFFFFFFull);
        int pk = ((idx >> 7) << 8) | (idx & 127);
        float tv = unsortable((unsigned)(f >> 32));
        if (w == 0) { taL[lane] = tv; paL[lane] = pk; }
        else        { taR[lane] = tv; paR[lane] = pk; }
    }
    if (t >= 128) wsv[t - 128] = Wp2[t - 128];
    float bp2v = bp2[0];
    __syncthreads();
    // publish pA for g4b (one block per unit)
    if ((bid & 7) == 0) {
        if (t < 64) pA[(2 * u) * 64 + t] = paL[t];
        else if (t < 128) pA[(2 * u + 1) * 64 + (t - 64)] = paR[t - 64];
    }
    // stage LsT (16 m of row 2u) and RsT (32 n of row 2u+1), S=2 means
    for (int i = t; i < 16 * 128; i += 256) {
        int m = i >> 7, h = i & 127;
        int pk = paL[mq * 16 + m]; int a0 = pk >> 8, a1 = pk & 255;
        float s = HP0[(size_t)(4 * u) * 16384 + a0 * 128 + h]
                + HP0[(size_t)(4 * u + 1) * 16384 + a1 * 128 + h];
        LsT[h][m] = s * 0.5f + bp1[h];
    }
    for (int i = t; i < 32 * 128; i += 256) {
        int n = i >> 7, h = i & 127;
        int pk = paR[nh * 32 + n]; int c0 = pk >> 8, c1 = pk & 255;
        float s = HP1[(size_t)(4 * u + 2) * 16384 + c0 * 128 + h]
                + HP1[(size_t)(4 * u + 3) * 16384 + c1 * 128 + h];
        RsT[h][n] = s * 0.5f;
    }
    __syncthreads();
    int lm = w * 4 + (lane >> 4);   // local m in [0,16)
    int ln = lane & 15;             // n pair: n_local = ln*2 + nj
    float a0 = 0.f, a1 = 0.f;
#pragma unroll 4
    for (int h = 0; h < 128; ++h) {
        float lv = LsT[h][lm];
        const float2 rv = *(const float2*)&RsT[h][ln * 2];
        float wv = wsv[h];
        float v;
        v = lv + rv.x; v = v > 0.f ? v : 0.f; a0 += v * wv;
        v = lv + rv.y; v = v > 0.f ? v : 0.f; a1 += v * wv;
    }
    int m_unit = mq * 16 + lm;
    int n0 = nh * 32 + ln * 2;
    float val0 = (taL[mq * 16 + lm] + taR[nh * 32 + ln * 2 + 0]) - (a0 + bp2v);
    float val1 = (taL[mq * 16 + lm] + taR[nh * 32 + ln * 2 + 1]) - (a1 + bp2v);
    u64 v0 = ((u64)sortable(val0) << 32) | (unsigned)(m_unit * 64 + n0);
    u64 v1 = ((u64)sortable(val1) << 32) | (unsigned)(m_unit * 64 + n0 + 1);
    sort128_reg(v0, v1, lane);
    cand[w][lane] = v0;   // wave's sorted top-64 of its 128 scores
    __syncthreads();
    if (w == 0) {
        u64 x0 = cand[0][lane], x1 = cand[1][lane];
        u64 x2 = cand[2][lane], x3 = cand[3][lane];
        u64 y0 = merge2(x0, x1, lane), y1 = merge2(x2, x3, lane);
        g4top[(size_t)bid * 64 + lane] = merge2(y0, y1, lane);
    }
}

// ---------------------------------------------------------------------------
// g4b: merge 8 chunk-lists/unit -> level-1 top-64; level-2 scoring (S=4) +
// argmin; output.  8 blocks x 512 (8 waves): both n-halves staged at once,
// no half-loop.  Per-element score expression identical -> exact argmin.
// ---------------------------------------------------------------------------
__global__ __launch_bounds__(512) void g4b_s2(
    const float* __restrict__ HP0, const float* __restrict__ HP1,
    const int* __restrict__ pA, const u64* __restrict__ g4top,
    const float* __restrict__ bp1, const float* __restrict__ Wp2,
    const float* __restrict__ bp2, float* __restrict__ outp) {
    int b = blockIdx.x;
    int t = threadIdx.x, lane = t & 63, w = t >> 6;
    __shared__ float LsT[128][68];
    __shared__ float RsT[128][68];
    __shared__ float tL[64], tR[64];
    __shared__ unsigned subL[64], subR[64];
    __shared__ float wsv[128];
    __shared__ u64 sred[8];
    if (t < 128) wsv[t] = Wp2[t];
    float bp2v = bp2[0];
    // merge 8 sorted lists per unit; wave0 -> unit 2b (L), wave1 -> 2b+1 (R)
    if (w < 2) {
        const u64* Lp = g4top + (size_t)(2 * b + w) * 512;
        u64 x0 = Lp[lane], x1 = Lp[64 + lane], x2 = Lp[128 + lane], x3 = Lp[192 + lane];
        u64 x4 = Lp[256 + lane], x5 = Lp[320 + lane], x6 = Lp[384 + lane], x7 = Lp[448 + lane];
        u64 y0 = merge2(x0, x1, lane), y1 = merge2(x2, x3, lane);
        u64 y2 = merge2(x4, x5, lane), y3 = merge2(x6, x7, lane);
        u64 z0 = merge2(y0, y1, lane), z1 = merge2(y2, y3, lane);
        u64 m = merge2(z0, z1, lane);
        int idx = (int)(m & 0xFFFFFFFFull);
        int p0 = idx >> 6, p1 = idx & 63;
        float val = unsortable((unsigned)(m >> 32));
        int rowL = 4 * b + 2 * w;
        int pkL = pA[rowL * 64 + p0];
        int pkR = pA[(rowL + 1) * 64 + p1];
        unsigned leaves = ((unsigned)pkL << 16) | (unsigned)pkR;  // bytes: a0,a1,c0,c1
        if (w == 0) { tL[lane] = val; subL[lane] = leaves; }
        else        { tR[lane] = val; subR[lane] = leaves; }
    }
    __syncthreads();
    // stage LsT: S=4 means from HP0 bks 8b..8b+3
    for (int i = t; i < 64 * 128; i += 512) {
        int m = i >> 7, h = i & 127;
        unsigned s4 = subL[m];
        float s = HP0[(size_t)(8 * b + 0) * 16384 + ((s4 >> 24) & 255u) * 128 + h]
                + HP0[(size_t)(8 * b + 1) * 16384 + ((s4 >> 16) & 255u) * 128 + h]
                + HP0[(size_t)(8 * b + 2) * 16384 + ((s4 >> 8) & 255u) * 128 + h]
                + HP0[(size_t)(8 * b + 3) * 16384 + (s4 & 255u) * 128 + h];
        LsT[h][m] = s * 0.25f + bp1[h];
    }
    // stage RsT: all 64 n
    for (int i = t; i < 64 * 128; i += 512) {
        int n = i >> 7, h = i & 127;
        unsigned s4 = subR[n];
        float s = HP1[(size_t)(8 * b + 4) * 16384 + ((s4 >> 24) & 255u) * 128 + h]
                + HP1[(size_t)(8 * b + 5) * 16384 + ((s4 >> 16) & 255u) * 128 + h]
                + HP1[(size_t)(8 * b + 6) * 16384 + ((s4 >> 8) & 255u) * 128 + h]
                + HP1[(size_t)(8 * b + 7) * 16384 + (s4 & 255u) * 128 + h];
        RsT[h][n] = s * 0.25f;
    }
    __syncthreads();
    // compute: 8 waves cover 64m x 64n; per thread 4m x 2n
    int qm = (w & 3) * 4 + (lane >> 4);     // [0,16): m = qm*4 + mi
    int qn = (w >> 2) * 16 + (lane & 15);   // [0,32): n = qn*2 + nj
    float acc[4][2];
#pragma unroll
    for (int i = 0; i < 4; ++i) { acc[i][0] = 0.f; acc[i][1] = 0.f; }
#pragma unroll 2
    for (int h = 0; h < 128; ++h) {
        const float4 lv = *(const float4*)&LsT[h][qm * 4];
        const float2 rv = *(const float2*)&RsT[h][qn * 2];
        float wv = wsv[h];
        float v;
        v = lv.x + rv.x; v = v > 0.f ? v : 0.f; acc[0][0] += v * wv;
        v = lv.x + rv.y; v = v > 0.f ? v : 0.f; acc[0][1] += v * wv;
        v = lv.y + rv.x; v = v > 0.f ? v : 0.f; acc[1][0] += v * wv;
        v = lv.y + rv.y; v = v > 0.f ? v : 0.f; acc[1][1] += v * wv;
        v = lv.z + rv.x; v = v > 0.f ? v : 0.f; acc[2][0] += v * wv;
        v = lv.z + rv.y; v = v > 0.f ? v : 0.f; acc[2][1] += v * wv;
        v = lv.w + rv.x; v = v > 0.f ? v : 0.f; acc[3][0] += v * wv;
        v = lv.w + rv.y; v = v > 0.f ? v : 0.f; acc[3][1] += v * wv;
    }
    u64 best = ~0ull;
#pragma unroll
    for (int mi = 0; mi < 4; ++mi) {
#pragma unroll
        for (int nj = 0; nj < 2; ++nj) {
            int m = qm * 4 + mi;
            int ng = qn * 2 + nj;
            float val = (tL[m] + tR[ng]) - (acc[mi][nj] + bp2v);
            u64 kk = ((u64)sortable(val) << 32) | (unsigned)(m * 64 + ng);
            best = kk < best ? kk : best;
        }
    }
#pragma unroll
    for (int off = 32; off > 0; off >>= 1) {
        u64 o = shfl_xor_u64(best, off);
        best = o < best ? o : best;
    }
    if (lane == 0) sred[w] = best;
    __syncthreads();
    if (t == 0) {
        u64 bb = sred[0];
        for (int p = 1; p < 8; ++p) { u64 o = sred[p]; bb = o < bb ? o : bb; }
        int idx = (int)(bb & 0xFFFFFFFFull);
        unsigned sl = subL[idx >> 6], sr = subR[idx & 63];
        outp[b * 8 + 0] = (float)((sl >> 24) & 255u);
        outp[b * 8 + 1] = (float)((sl >> 16) & 255u);
        outp[b * 8 + 2] = (float)((sl >> 8) & 255u);
        outp[b * 8 + 3] = (float)(sl & 255u);
        outp[b * 8 + 4] = (float)((sr >> 24) & 255u);
        outp[b * 8 + 5] = (float)((sr >> 16) & 255u);
        outp[b * 8 + 6] = (float)((sr >> 8) & 255u);
        outp[b * 8 + 7] = (float)(sr & 255u);
    }
}

extern "C" void kernel_launch(void* const* d_in, const int* in_sizes, int n_in,
                              void* d_out, int out_size, void* d_ws, size_t ws_size,
                              hipStream_t stream) {
    const float* pos = (const float*)d_in[0];
    const float* neg = (const float*)d_in[1];
    const int* pos_classes = (const int*)d_in[2];
    const int* target_class = (const int*)d_in[3];
    const float* Wp1 = (const float*)d_in[4];
    const float* bp1 = (const float*)d_in[5];
    const float* Wp2 = (const float*)d_in[6];
    const float* bp2 = (const float*)d_in[7];
    const float* Wu1 = (const float*)d_in[8];
    const float* bu1 = (const float*)d_in[9];
    const float* Wu2 = (const float*)d_in[10];
    const float* bu2 = (const float*)d_in[11];

    float* wsf = (float*)d_ws;
    float* HU0 = wsf;                       // 1048576 (free after g2 -> reused)
    float* HP0 = HU0 + 1048576;             // 1048576
    float* HP1 = HP0 + 1048576;             // 1048576
    float* HU1n = HP1 + 1048576;            // 524288
    float* t0 = HU1n + 524288;              // 8192
    float* sc0 = t0 + 8192;                 // 524288
    int* pA = (int*)(sc0 + 524288);         // 2048
    // g3c/g4top overlay the HU0 region (only needed after g2's last HU0 read)
    u64* g3c = (u64*)wsf;                   // 256*64 u64 = 128 KB
    u64* g4top = (u64*)wsf + 16384;         // 128*64 u64 = 64 KB
    float* outp = (float*)d_out;

    g1_gemm<<<900, 64, 0, stream>>>(pos, neg, Wu1, Wp1, pos_classes,
                                    target_class, HU0, HU1n, HP0, HP1, outp);
    g2_ue_sc0<<<512, 128, 0, stream>>>(HU0, HU1n, bu1, Wu2, bu2,
                                       HP0, HP1, bp1, Wp2, bp2, t0, sc0);
    g3a_top0<<<256, 256, 0, stream>>>(sc0, t0, g3c);
    g4a_s1<<<128, 256, 0, stream>>>(HP0, HP1, g3c, pA, bp1, Wp2, bp2, g4top);
    g4b_s2<<<8, 512, 0, stream>>>(HP0, HP1, pA, g4top, bp1, Wp2, bp2, outp);
}

// Round 8
// 167.322 us; speedup vs baseline: 1.8221x; 1.8221x over previous
//
#include <hip/hip_runtime.h>
#include <stdint.h>

#define B_ 8
#define K_ 8
#define N_ 128
#define D_ 256
#define H_ 128
#define NNEG_ 64

typedef unsigned long long u64;
typedef float f4 __attribute__((ext_vector_type(4)));

// ---------------------------------------------------------------------------
// u64 wave shuffles + bitonic helpers
// ---------------------------------------------------------------------------
__device__ __forceinline__ u64 shfl_xor_u64(u64 v, int m) {
    int lo = __shfl_xor((int)(unsigned)v, m, 64);
    int hi = __shfl_xor((int)(unsigned)(v >> 32), m, 64);
    return ((u64)(unsigned)hi << 32) | (unsigned)lo;
}
// cleanup merge of a bitonic 64-seq -> ascending across lanes
__device__ __forceinline__ u64 bitonic_merge64(u64 m, int lane) {
#pragma unroll
    for (int j = 32; j > 0; j >>= 1) {
        u64 o = shfl_xor_u64(m, j);
        bool keepMin = ((lane & j) == 0);
        bool lt = m < o;
        m = (keepMin == lt) ? m : o;
    }
    return m;
}
// top-64 of union of two ascending sorted 64-lists (one elem/lane), ascending
__device__ __forceinline__ u64 merge2(u64 a, u64 b, int lane) {
    u64 br = shfl_xor_u64(b, 63);   // b[63-lane]
    u64 m = a < br ? a : br;
    return bitonic_merge64(m, lane);
}
__device__ __forceinline__ unsigned sortable(float f) {
    unsigned u = __float_as_uint(f);
    return (u & 0x80000000u) ? ~u : (u | 0x80000000u);
}
__device__ __forceinline__ float unsortable(unsigned u) {
    return __uint_as_float((u & 0x80000000u) ? (u & 0x7FFFFFFFu) : ~u);
}
// full ascending sort of 128 elems held 2/lane in registers (wave-local)
__device__ __forceinline__ void sort128_reg(u64& v0, u64& v1, int lane) {
#pragma unroll
    for (int k = 2; k <= 64; k <<= 1) {
        bool d0 = ((lane & k) == 0);
        bool d1 = (k == 64) ? false : d0;
#pragma unroll
        for (int j = k >> 1; j > 0; j >>= 1) {
            u64 o0 = shfl_xor_u64(v0, j);
            bool km0 = (((lane & j) == 0) == d0);
            v0 = (km0 == (v0 < o0)) ? v0 : o0;
            u64 o1 = shfl_xor_u64(v1, j);
            bool km1 = (((lane & j) == 0) == d1);
            v1 = (km1 == (v1 < o1)) ? v1 : o1;
        }
    }
    if (v0 > v1) { u64 tmp = v0; v0 = v1; v1 = tmp; }
#pragma unroll
    for (int j = 32; j > 0; j >>= 1) {
        bool km = ((lane & j) == 0);
        u64 o0 = shfl_xor_u64(v0, j);
        v0 = (km == (v0 < o0)) ? v0 : o0;
        u64 o1 = shfl_xor_u64(v1, j);
        v1 = (km == (v1 < o1)) ? v1 : o1;
    }
}

// ---------------------------------------------------------------------------
// g1: 4 GEMMs + is_target.  64x64 tiles, 128 threads (2 waves), 4x8/thread.
// Double-buffered LDS with register prefetch: ONE barrier per K-chunk.
// (Exact version from the best 173.08us run.)  VGPR ~100, no spill.
// K ascending per output -> accumulation order identical -> bit-exact.
// Blocks: [0,256) HU0, [256,384) HU1n, [384,640) HP0, [640,896) HP1,
// [896,900) is_target.  bid2 = 2*rowtile + colhalf.
// ---------------------------------------------------------------------------
__global__ __launch_bounds__(128) void g1_gemm(
    const float* __restrict__ pos, const float* __restrict__ neg,
    const float* __restrict__ Wu1, const float* __restrict__ Wp1,
    const int* __restrict__ pos_classes, const int* __restrict__ target_class,
    float* __restrict__ HU0, float* __restrict__ HU1n,
    float* __restrict__ HP0, float* __restrict__ HP1,
    float* __restrict__ outp) {
    int bid = blockIdx.x;
    int t = threadIdx.x;
    if (bid >= 896) {
        int base = (bid - 896) * 2048 + t * 16;
#pragma unroll
        for (int q = 0; q < 16; ++q) {
            int idx = base + q;
            outp[64 + idx] = (pos_classes[idx] == target_class[idx >> 10]) ? 1.0f : 0.0f;
        }
        return;
    }
    const float* A; const float* W; float* OUT; int bid2;
    if (bid < 256)      { A = pos; W = Wu1;           OUT = HU0;  bid2 = bid; }
    else if (bid < 384) { A = neg; W = Wu1 + D_ * H_; OUT = HU1n; bid2 = bid - 256; }
    else if (bid < 640) { A = pos; W = Wp1;           OUT = HP0;  bid2 = bid - 384; }
    else                { A = pos; W = Wp1 + D_ * H_; OUT = HP1;  bid2 = bid - 640; }
    int rb = (bid2 >> 1) * 64;      // row base
    int cb64 = (bid2 & 1) * 64;     // col base (0 or 64)

    __shared__ float AsT[2][32][68];   // [buf][kk][row]
    __shared__ float Bs[2][32][64];    // [buf][kk][col_local]
    int tx = t & 7, ty = t >> 3;       // tx: 8 col-octs; ty: 16 row-quads
    float acc[4][8];
#pragma unroll
    for (int i = 0; i < 4; ++i)
#pragma unroll
        for (int j = 0; j < 8; ++j) acc[i][j] = 0.f;

    // prologue: stage chunk 0 directly into buffer 0
#pragma unroll
    for (int rep = 0; rep < 4; ++rep) {
        int flat = t + rep * 128;          // 0..511
        int row = flat >> 3, kq = flat & 7;
        const float4 av = *(const float4*)&A[(size_t)(rb + row) * D_ + kq * 4];
        AsT[0][kq * 4 + 0][row] = av.x;
        AsT[0][kq * 4 + 1][row] = av.y;
        AsT[0][kq * 4 + 2][row] = av.z;
        AsT[0][kq * 4 + 3][row] = av.w;
    }
#pragma unroll
    for (int rep = 0; rep < 4; ++rep) {
        int flat = t + rep * 128;          // 0..511
        int kr = flat >> 4, cq = flat & 15;
        *(float4*)&Bs[0][kr][cq * 4] =
            *(const float4*)&W[(size_t)kr * H_ + cb64 + cq * 4];
    }
    __syncthreads();

    for (int chunk = 0; chunk < 8; ++chunk) {
        int cur = chunk & 1, nxt = cur ^ 1;
        bool pre = (chunk < 7);
        int k0n = (chunk + 1) * 32;
        float4 pa[4], pb[4];
        if (pre) {
            // issue next-chunk global loads early; latency hides under compute
#pragma unroll
            for (int rep = 0; rep < 4; ++rep) {
                int flat = t + rep * 128;
                int row = flat >> 3, kq = flat & 7;
                pa[rep] = *(const float4*)&A[(size_t)(rb + row) * D_ + k0n + kq * 4];
            }
#pragma unroll
            for (int rep = 0; rep < 4; ++rep) {
                int flat = t + rep * 128;
                int kr = flat >> 4, cq = flat & 15;
                pb[rep] = *(const float4*)&W[(size_t)(k0n + kr) * H_ + cb64 + cq * 4];
            }
        }
#pragma unroll 8
        for (int kk = 0; kk < 32; ++kk) {
            const float4 av = *(const float4*)&AsT[cur][kk][ty * 4];
            float bv[8];
            *(float4*)&bv[0] = *(const float4*)&Bs[cur][kk][tx * 8];
            *(float4*)&bv[4] = *(const float4*)&Bs[cur][kk][tx * 8 + 4];
#pragma unroll
            for (int j = 0; j < 8; ++j) {
                acc[0][j] += av.x * bv[j];
                acc[1][j] += av.y * bv[j];
                acc[2][j] += av.z * bv[j];
                acc[3][j] += av.w * bv[j];
            }
        }
        if (pre) {
#pragma unroll
            for (int rep = 0; rep < 4; ++rep) {
                int flat = t + rep * 128;
                int row = flat >> 3, kq = flat & 7;
                AsT[nxt][kq * 4 + 0][row] = pa[rep].x;
                AsT[nxt][kq * 4 + 1][row] = pa[rep].y;
                AsT[nxt][kq * 4 + 2][row] = pa[rep].z;
                AsT[nxt][kq * 4 + 3][row] = pa[rep].w;
            }
#pragma unroll
            for (int rep = 0; rep < 4; ++rep) {
                int flat = t + rep * 128;
                int kr = flat >> 4, cq = flat & 15;
                *(float4*)&Bs[nxt][kr][cq * 4] = pb[rep];
            }
        }
        __syncthreads();
    }
#pragma unroll
    for (int i = 0; i < 4; ++i) {
        float4 o0 = {acc[i][0], acc[i][1], acc[i][2], acc[i][3]};
        float4 o1 = {acc[i][4], acc[i][5], acc[i][6], acc[i][7]};
        *(float4*)&OUT[(size_t)(rb + ty * 4 + i) * H_ + cb64 + tx * 8] = o0;
        *(float4*)&OUT[(size_t)(rb + ty * 4 + i) * H_ + cb64 + tx * 8 + 4] = o1;
    }
}

// ---------------------------------------------------------------------------
// g2: blocks 0..255 = ue (t0), blocks 256..511 = score0 (sc0 = dot + bp2).
// 128 threads, 4m x 4n per thread.  ue reduction tree identical to prior
// rounds -> bit-exact.  sc0: h ascending -> bit-exact.
// (Validated at absmax 0.0 in rounds 6 and 7.)
// ---------------------------------------------------------------------------
__global__ __launch_bounds__(128) void g2_ue_sc0(
    const float* __restrict__ HU0, const float* __restrict__ HU1n,
    const float* __restrict__ bu1, const float* __restrict__ Wu2,
    const float* __restrict__ bu2v,
    const float* __restrict__ HP0, const float* __restrict__ HP1,
    const float* __restrict__ bp1, const float* __restrict__ Wp2,
    const float* __restrict__ bp2,
    float* __restrict__ t0, float* __restrict__ sc0) {
    __shared__ float LsT[128][36];   // [h][m], m<32
    __shared__ float RsT[128][68];   // [h][n], n<64
    __shared__ float wsv[128];
    __shared__ float red[32][33];

    int bid = blockIdx.x;
    int t = threadIdx.x;
    bool is_ue = bid < 256;

    const float* Lsrc; const float* Rsrc; const float* b1v; const float* W2;
    if (is_ue) {
        int bk = bid >> 2, mt = bid & 3;
        Lsrc = HU0 + (size_t)(bk * N_ + mt * 32) * H_;
        Rsrc = HU1n + (size_t)bk * NNEG_ * H_;
        b1v = bu1; W2 = Wu2;
    } else {
        int bid2 = bid - 256;
        int b = bid2 >> 3, m0t = (bid2 >> 1) & 3, m1t = bid2 & 1;
        Lsrc = HP0 + (size_t)b * 2 * N_ * H_ + m0t * 32 * H_;
        Rsrc = HP1 + (size_t)b * 2 * N_ * H_ + N_ * H_ + m1t * 64 * H_;
        b1v = bp1; W2 = Wp2;
    }
    // stage L transposed (+b1): 32 m x 32 h-quads; m-fastest (conflict-free)
    for (int i = t; i < 32 * 32; i += 128) {
        int m = i & 31, hq = i >> 5;
        const f4 a = *(const f4*)&Lsrc[(size_t)m * H_ + hq * 4];
        const f4 b = *(const f4*)&b1v[hq * 4];
        LsT[hq * 4 + 0][m] = a[0] + b[0];
        LsT[hq * 4 + 1][m] = a[1] + b[1];
        LsT[hq * 4 + 2][m] = a[2] + b[2];
        LsT[hq * 4 + 3][m] = a[3] + b[3];
    }
    // stage R transposed: 64 n x 32 h-quads; n-fastest (2-way = free)
    for (int i = t; i < 64 * 32; i += 128) {
        int n = i & 63, hq = i >> 6;
        const f4 a = *(const f4*)&Rsrc[(size_t)n * H_ + hq * 4];
        RsT[hq * 4 + 0][n] = a[0];
        RsT[hq * 4 + 1][n] = a[1];
        RsT[hq * 4 + 2][n] = a[2];
        RsT[hq * 4 + 3][n] = a[3];
    }
    wsv[t] = W2[t];
    __syncthreads();

    int tm = t & 7, tn = t >> 3;    // m = tm*4+i (32), n = tn*4+j (64)
    f4 acc[4];
#pragma unroll
    for (int i = 0; i < 4; ++i) acc[i] = (f4)0.f;
#pragma unroll 2
    for (int hg = 0; hg < 32; ++hg) {
        f4 wv = *(const f4*)&wsv[hg * 4];
        f4 lv[4], rv[4];
#pragma unroll
        for (int s = 0; s < 4; ++s) {
            lv[s] = *(const f4*)&LsT[hg * 4 + s][tm * 4];
            rv[s] = *(const f4*)&RsT[hg * 4 + s][tn * 4];
        }
#pragma unroll
        for (int s = 0; s < 4; ++s) {
            float w = wv[s];
#pragma unroll
            for (int i = 0; i < 4; ++i) {
                float l = lv[s][i];
                float v;
                v = l + rv[s][0]; v = v > 0.f ? v : 0.f; acc[i][0] += v * w;
                v = l + rv[s][1]; v = v > 0.f ? v : 0.f; acc[i][1] += v * w;
                v = l + rv[s][2]; v = v > 0.f ? v : 0.f; acc[i][2] += v * w;
                v = l + rv[s][3]; v = v > 0.f ? v : 0.f; acc[i][3] += v * w;
            }
        }
    }

    if (is_ue) {
        int bk = bid >> 2, mt = bid & 3;
#pragma unroll
        for (int i = 0; i < 4; ++i) {
            red[tm * 4 + i][tn * 2 + 0] = acc[i][0] + acc[i][1];
            red[tm * 4 + i][tn * 2 + 1] = acc[i][2] + acc[i][3];
        }
        __syncthreads();
        if (t < 32) {
            float s = 0.f;
            for (int q = 0; q < 32; ++q) s += red[t][q];
            t0[bk * N_ + mt * 32 + t] = s * (1.0f / NNEG_) + bu2v[0];
        }
    } else {
        int bid2 = bid - 256;
        int b = bid2 >> 3, m0t = (bid2 >> 1) & 3, m1t = bid2 & 1;
        float bp2v = bp2[0];
        float* orow = sc0 + (size_t)b * 16384;
#pragma unroll
        for (int i = 0; i < 4; ++i) {
            int m0 = m0t * 32 + tm * 4 + i;
            int m1 = m1t * 64 + tn * 4;
            f4 o = {acc[i][0] + bp2v, acc[i][1] + bp2v,
                    acc[i][2] + bp2v, acc[i][3] + bp2v};
            *(f4*)&orow[m0 * 128 + m1] = o;
        }
    }
}

// ---------------------------------------------------------------------------
// g3a: level-0 chunk top-64.  256 blocks (row r, chunk c of 8) x 256.
// Per-wave ballot radix-descent -> compact -> register sort-128 -> merge 4.
// ---------------------------------------------------------------------------
__global__ __launch_bounds__(256) void g3a_top0(const float* __restrict__ sc0,
                                                const float* __restrict__ t0,
                                                u64* __restrict__ g3c) {
    int bid = blockIdx.x;
    int r = bid >> 3, c = bid & 7;
    int t = threadIdx.x, lane = t & 63, w = t >> 6;
    __shared__ float tt[256];
    __shared__ u64 cand[4][128];
    if (t < 256) tt[t] = t0[r * 256 + t];
    __syncthreads();
    const float* row = sc0 + (size_t)r * 16384 + c * 2048 + w * 512;
    unsigned sv[8];
#pragma unroll
    for (int j = 0; j < 8; ++j) {
        int li = j * 64 + lane;
        int idx = c * 2048 + w * 512 + li;
        float v = (tt[idx >> 7] + tt[128 + (idx & 127)]) - row[li];
        sv[j] = sortable(v);
    }
    // per-wave exact rank-63 threshold over this wave's 512 values
    unsigned T = 0u;
#pragma unroll
    for (int it = 0; it < 16; ++it) {
        int p = 30 - 2 * it;
        unsigned C1 = T | (1u << p), C2 = T | (2u << p), C3 = T | (3u << p);
        unsigned c1 = 0u, c2 = 0u, c3 = 0u;
#pragma unroll
        for (int j = 0; j < 8; ++j) {
            c1 += (unsigned)__popcll(__ballot(sv[j] < C1));
            c2 += (unsigned)__popcll(__ballot(sv[j] < C2));
            c3 += (unsigned)__popcll(__ballot(sv[j] < C3));
        }
        unsigned k = (c3 < 64u) ? 3u : (c2 < 64u) ? 2u : (c1 < 64u) ? 1u : 0u;
        T |= (k << p);
    }
    // compact candidates (sv <= T), deterministic ballot-prefix, cap 128
    u64* my = cand[w];
    int base = 0;
#pragma unroll
    for (int j = 0; j < 8; ++j) {
        u64 mask = __ballot(sv[j] <= T);
        if (sv[j] <= T) {
            int pos = base + (int)__popcll(mask & ((1ull << lane) - 1ull));
            if (pos < 128) {
                int idx = c * 2048 + w * 512 + j * 64 + lane;
                my[pos] = ((u64)sv[j] << 32) | (unsigned)idx;
            }
        }
        base += (int)__popcll(mask);
    }
    int cc = base < 128 ? base : 128;
    u64 v0 = (lane < cc) ? my[lane] : ~0ull;
    u64 v1 = (64 + lane < cc) ? my[64 + lane] : ~0ull;
    sort128_reg(v0, v1, lane);
    my[lane] = v0;   // wave's sorted top-64
    __syncthreads();
    if (w == 0) {
        u64 x0 = cand[0][lane], x1 = cand[1][lane];
        u64 x2 = cand[2][lane], x3 = cand[3][lane];
        u64 y0 = merge2(x0, x1, lane), y1 = merge2(x2, x3, lane);
        g3c[(size_t)bid * 64 + lane] = merge2(y0, y1, lane);
    }
}

// ---------------------------------------------------------------------------
// g4a: (fused g3b) row-merge + level-1 scoring + chunk top-64.
// 128 blocks (unit u, m-quarter mq, n-half nh) x 256.
// ---------------------------------------------------------------------------
__global__ __launch_bounds__(256) void g4a_s1(
    const float* __restrict__ HP0, const float* __restrict__ HP1,
    const u64* __restrict__ g3c, int* __restrict__ pA,
    const float* __restrict__ bp1, const float* __restrict__ Wp2,
    const float* __restrict__ bp2, u64* __restrict__ g4top) {
    int bid = blockIdx.x;
    int u = bid >> 3, mq = (bid >> 1) & 3, nh = bid & 1;
    int t = threadIdx.x, lane = t & 63, w = t >> 6;
    __shared__ float LsT[128][17];   // [h][m_local], 16 m rows
    __shared__ float RsT[128][34];   // [h][n_local], 32 n cols
    __shared__ float taL[64], taR[64];
    __shared__ int paL[64], paR[64];
    __shared__ float wsv[128];
    __shared__ u64 cand[4][64];
    // fused g3b: waves 0/1 merge rows 2u / 2u+1 (8 sorted 64-lists each)
    if (w < 2) {
        const u64* Lp = g3c + (size_t)(2 * u + w) * 512;
        u64 x0 = Lp[lane], x1 = Lp[64 + lane], x2 = Lp[128 + lane], x3 = Lp[192 + lane];
        u64 x4 = Lp[256 + lane], x5 = Lp[320 + lane], x6 = Lp[384 + lane], x7 = Lp[448 + lane];
        u64 y0 = merge2(x0, x1, lane), y1 = merge2(x2, x3, lane);
        u64 y2 = merge2(x4, x5, lane), y3 = merge2(x6, x7, lane);
        u64 z0 = merge2(y0, y1, lane), z1 = merge2(y2, y3, lane);
        u64 f = merge2(z0, z1, lane);
        int idx = (int)(f & 0xFFFFFFFFull);
        int pk = ((idx >> 7) << 8) | (idx & 127);
        float tv = unsortable((unsigned)(f >> 32));
        if (w == 0) { taL[lane] = tv; paL[lane] = pk; }
        else        { taR[lane] = tv; paR[lane] = pk; }
    }
    if (t >= 128) wsv[t - 128] = Wp2[t - 128];
    float bp2v = bp2[0];
    __syncthreads();
    // publish pA for g4b (one block per unit)
    if ((bid & 7) == 0) {
        if (t < 64) pA[(2 * u) * 64 + t] = paL[t];
        else if (t < 128) pA[(2 * u + 1) * 64 + (t - 64)] = paR[t - 64];
    }
    // stage LsT (16 m of row 2u) and RsT (32 n of row 2u+1), S=2 means
    for (int i = t; i < 16 * 128; i += 256) {
        int m = i >> 7, h = i & 127;
        int pk = paL[mq * 16 + m]; int a0 = pk >> 8, a1 = pk & 255;
        float s = HP0[(size_t)(4 * u) * 16384 + a0 * 128 + h]
                + HP0[(size_t)(4 * u + 1) * 16384 + a1 * 128 + h];
        LsT[h][m] = s * 0.5f + bp1[h];
    }
    for (int i = t; i < 32 * 128; i += 256) {
        int n = i >> 7, h = i & 127;
        int pk = paR[nh * 32 + n]; int c0 = pk >> 8, c1 = pk & 255;
        float s = HP1[(size_t)(4 * u + 2) * 16384 + c0 * 128 + h]
                + HP1[(size_t)(4 * u + 3) * 16384 + c1 * 128 + h];
        RsT[h][n] = s * 0.5f;
    }
    __syncthreads();
    int lm = w * 4 + (lane >> 4);   // local m in [0,16)
    int ln = lane & 15;             // n pair: n_local = ln*2 + nj
    float a0 = 0.f, a1 = 0.f;
#pragma unroll 4
    for (int h = 0; h < 128; ++h) {
        float lv = LsT[h][lm];
        const float2 rv = *(const float2*)&RsT[h][ln * 2];
        float wv = wsv[h];
        float v;
        v = lv + rv.x; v = v > 0.f ? v : 0.f; a0 += v * wv;
        v = lv + rv.y; v = v > 0.f ? v : 0.f; a1 += v * wv;
    }
    int m_unit = mq * 16 + lm;
    int n0 = nh * 32 + ln * 2;
    float val0 = (taL[mq * 16 + lm] + taR[nh * 32 + ln * 2 + 0]) - (a0 + bp2v);
    float val1 = (taL[mq * 16 + lm] + taR[nh * 32 + ln * 2 + 1]) - (a1 + bp2v);
    u64 v0 = ((u64)sortable(val0) << 32) | (unsigned)(m_unit * 64 + n0);
    u64 v1 = ((u64)sortable(val1) << 32) | (unsigned)(m_unit * 64 + n0 + 1);
    sort128_reg(v0, v1, lane);
    cand[w][lane] = v0;   // wave's sorted top-64 of its 128 scores
    __syncthreads();
    if (w == 0) {
        u64 x0 = cand[0][lane], x1 = cand[1][lane];
        u64 x2 = cand[2][lane], x3 = cand[3][lane];
        u64 y0 = merge2(x0, x1, lane), y1 = merge2(x2, x3, lane);
        g4top[(size_t)bid * 64 + lane] = merge2(y0, y1, lane);
    }
}

// ---------------------------------------------------------------------------
// g4b: merge 8 chunk-lists/unit -> level-1 top-64; level-2 scoring (S=4) +
// argmin; output.  8 blocks x 512 (8 waves): both n-halves staged at once,
// no half-loop.  (Validated at absmax 0.0 in round 7.)
// ---------------------------------------------------------------------------
__global__ __launch_bounds__(512) void g4b_s2(
    const float* __restrict__ HP0, const float* __restrict__ HP1,
    const int* __restrict__ pA, const u64* __restrict__ g4top,
    const float* __restrict__ bp1, const float* __restrict__ Wp2,
    const float* __restrict__ bp2, float* __restrict__ outp) {
    int b = blockIdx.x;
    int t = threadIdx.x, lane = t & 63, w = t >> 6;
    __shared__ float LsT[128][68];
    __shared__ float RsT[128][68];
    __shared__ float tL[64], tR[64];
    __shared__ unsigned subL[64], subR[64];
    __shared__ float wsv[128];
    __shared__ u64 sred[8];
    if (t < 128) wsv[t] = Wp2[t];
    float bp2v = bp2[0];
    // merge 8 sorted lists per unit; wave0 -> unit 2b (L), wave1 -> 2b+1 (R)
    if (w < 2) {
        const u64* Lp = g4top + (size_t)(2 * b + w) * 512;
        u64 x0 = Lp[lane], x1 = Lp[64 + lane], x2 = Lp[128 + lane], x3 = Lp[192 + lane];
        u64 x4 = Lp[256 + lane], x5 = Lp[320 + lane], x6 = Lp[384 + lane], x7 = Lp[448 + lane];
        u64 y0 = merge2(x0, x1, lane), y1 = merge2(x2, x3, lane);
        u64 y2 = merge2(x4, x5, lane), y3 = merge2(x6, x7, lane);
        u64 z0 = merge2(y0, y1, lane), z1 = merge2(y2, y3, lane);
        u64 m = merge2(z0, z1, lane);
        int idx = (int)(m & 0xFFFFFFFFull);
        int p0 = idx >> 6, p1 = idx & 63;
        float val = unsortable((unsigned)(m >> 32));
        int rowL = 4 * b + 2 * w;
        int pkL = pA[rowL * 64 + p0];
        int pkR = pA[(rowL + 1) * 64 + p1];
        unsigned leaves = ((unsigned)pkL << 16) | (unsigned)pkR;  // bytes: a0,a1,c0,c1
        if (w == 0) { tL[lane] = val; subL[lane] = leaves; }
        else        { tR[lane] = val; subR[lane] = leaves; }
    }
    __syncthreads();
    // stage LsT: S=4 means from HP0 bks 8b..8b+3
    for (int i = t; i < 64 * 128; i += 512) {
        int m = i >> 7, h = i & 127;
        unsigned s4 = subL[m];
        float s = HP0[(size_t)(8 * b + 0) * 16384 + ((s4 >> 24) & 255u) * 128 + h]
                + HP0[(size_t)(8 * b + 1) * 16384 + ((s4 >> 16) & 255u) * 128 + h]
                + HP0[(size_t)(8 * b + 2) * 16384 + ((s4 >> 8) & 255u) * 128 + h]
                + HP0[(size_t)(8 * b + 3) * 16384 + (s4 & 255u) * 128 + h];
        LsT[h][m] = s * 0.25f + bp1[h];
    }
    // stage RsT: all 64 n
    for (int i = t; i < 64 * 128; i += 512) {
        int n = i >> 7, h = i & 127;
        unsigned s4 = subR[n];
        float s = HP1[(size_t)(8 * b + 4) * 16384 + ((s4 >> 24) & 255u) * 128 + h]
                + HP1[(size_t)(8 * b + 5) * 16384 + ((s4 >> 16) & 255u) * 128 + h]
                + HP1[(size_t)(8 * b + 6) * 16384 + ((s4 >> 8) & 255u) * 128 + h]
                + HP1[(size_t)(8 * b + 7) * 16384 + (s4 & 255u) * 128 + h];
        RsT[h][n] = s * 0.25f;
    }
    __syncthreads();
    // compute: 8 waves cover 64m x 64n; per thread 4m x 2n
    int qm = (w & 3) * 4 + (lane >> 4);     // [0,16): m = qm*4 + mi
    int qn = (w >> 2) * 16 + (lane & 15);   // [0,32): n = qn*2 + nj
    float acc[4][2];
#pragma unroll
    for (int i = 0; i < 4; ++i) { acc[i][0] = 0.f; acc[i][1] = 0.f; }
#pragma unroll 2
    for (int h = 0; h < 128; ++h) {
        const float4 lv = *(const float4*)&LsT[h][qm * 4];
        const float2 rv = *(const float2*)&RsT[h][qn * 2];
        float wv = wsv[h];
        float v;
        v = lv.x + rv.x; v = v > 0.f ? v : 0.f; acc[0][0] += v * wv;
        v = lv.x + rv.y; v = v > 0.f ? v : 0.f; acc[0][1] += v * wv;
        v = lv.y + rv.x; v = v > 0.f ? v : 0.f; acc[1][0] += v * wv;
        v = lv.y + rv.y; v = v > 0.f ? v : 0.f; acc[1][1] += v * wv;
        v = lv.z + rv.x; v = v > 0.f ? v : 0.f; acc[2][0] += v * wv;
        v = lv.z + rv.y; v = v > 0.f ? v : 0.f; acc[2][1] += v * wv;
        v = lv.w + rv.x; v = v > 0.f ? v : 0.f; acc[3][0] += v * wv;
        v = lv.w + rv.y; v = v > 0.f ? v : 0.f; acc[3][1] += v * wv;
    }
    u64 best = ~0ull;
#pragma unroll
    for (int mi = 0; mi < 4; ++mi) {
#pragma unroll
        for (int nj = 0; nj < 2; ++nj) {
            int m = qm * 4 + mi;
            int ng = qn * 2 + nj;
            float val = (tL[m] + tR[ng]) - (acc[mi][nj] + bp2v);
            u64 kk = ((u64)sortable(val) << 32) | (unsigned)(m * 64 + ng);
            best = kk < best ? kk : best;
        }
    }
#pragma unroll
    for (int off = 32; off > 0; off >>= 1) {
        u64 o = shfl_xor_u64(best, off);
        best = o < best ? o : best;
    }
    if (lane == 0) sred[w] = best;
    __syncthreads();
    if (t == 0) {
        u64 bb = sred[0];
        for (int p = 1; p < 8; ++p) { u64 o = sred[p]; bb = o < bb ? o : bb; }
        int idx = (int)(bb & 0xFFFFFFFFull);
        unsigned sl = subL[idx >> 6], sr = subR[idx & 63];
        outp[b * 8 + 0] = (float)((sl >> 24) & 255u);
        outp[b * 8 + 1] = (float)((sl >> 16) & 255u);
        outp[b * 8 + 2] = (float)((sl >> 8) & 255u);
        outp[b * 8 + 3] = (float)(sl & 255u);
        outp[b * 8 + 4] = (float)((sr >> 24) & 255u);
        outp[b * 8 + 5] = (float)((sr >> 16) & 255u);
        outp[b * 8 + 6] = (float)((sr >> 8) & 255u);
        outp[b * 8 + 7] = (float)(sr & 255u);
    }
}

extern "C" void kernel_launch(void* const* d_in, const int* in_sizes, int n_in,
                              void* d_out, int out_size, void* d_ws, size_t ws_size,
                              hipStream_t stream) {
    const float* pos = (const float*)d_in[0];
    const float* neg = (const float*)d_in[1];
    const int* pos_classes = (const int*)d_in[2];
    const int* target_class = (const int*)d_in[3];
    const float* Wp1 = (const float*)d_in[4];
    const float* bp1 = (const float*)d_in[5];
    const float* Wp2 = (const float*)d_in[6];
    const float* bp2 = (const float*)d_in[7];
    const float* Wu1 = (const float*)d_in[8];
    const float* bu1 = (const float*)d_in[9];
    const float* Wu2 = (const float*)d_in[10];
    const float* bu2 = (const float*)d_in[11];

    float* wsf = (float*)d_ws;
    float* HU0 = wsf;                       // 1048576 (free after g2 -> reused)
    float* HP0 = HU0 + 1048576;             // 1048576
    float* HP1 = HP0 + 1048576;             // 1048576
    float* HU1n = HP1 + 1048576;            // 524288
    float* t0 = HU1n + 524288;              // 8192
    float* sc0 = t0 + 8192;                 // 524288
    int* pA = (int*)(sc0 + 524288);         // 2048
    // g3c/g4top overlay the HU0 region (only needed after g2's last HU0 read)
    u64* g3c = (u64*)wsf;                   // 256*64 u64 = 128 KB
    u64* g4top = (u64*)wsf + 16384;         // 128*64 u64 = 64 KB
    float* outp = (float*)d_out;

    g1_gemm<<<900, 128, 0, stream>>>(pos, neg, Wu1, Wp1, pos_classes,
                                     target_class, HU0, HU1n, HP0, HP1, outp);
    g2_ue_sc0<<<512, 128, 0, stream>>>(HU0, HU1n, bu1, Wu2, bu2,
                                       HP0, HP1, bp1, Wp2, bp2, t0, sc0);
    g3a_top0<<<256, 256, 0, stream>>>(sc0, t0, g3c);
    g4a_s1<<<128, 256, 0, stream>>>(HP0, HP1, g3c, pA, bp1, Wp2, bp2, g4top);
    g4b_s2<<<8, 512, 0, stream>>>(HP0, HP1, pA, g4top, bp1, Wp2, bp2, outp);
}